// Round 4
// baseline (346.691 us; speedup 1.0000x reference)
//
#include <hip/hip_runtime.h>
#include <hip/hip_bf16.h>
#include <math.h>

// Problem constants
#define NPTS 65536
#define DIM  256
#define KC   512

// som_main geometry
#define BM   256    // points per block
#define NBLK (NPTS / BM)          // 256 blocks = 1 per CU
#define DSL  64     // D slice (floats) staged in LDS at a time
#define LSTR 68     // LDS row stride in dwords: 272 B = 16B-aligned, bank shift 4/row

// d_out layout (floats): [0]=loss, [1..1+16777216)=quantized, [16777217]=perplexity,
// [16777218..+65536)=enc_idx (as float)
#define QOFF  1
#define PIDX  16777217
#define EOFF  16777218

// d_ws layout: wsq f32[512] @0, g f32[512] @512, hist i32[512] @1024, mse f64 @byte 6144

// ---------------- prep: wsq[k] = |w_k|^2, zero hist + mse ----------------
__global__ __launch_bounds__(256) void som_prep(const float* __restrict__ w,
                                                float* __restrict__ wsq,
                                                int* __restrict__ hist,
                                                double* __restrict__ mse_acc)
{
    int k = blockIdx.x * 256 + threadIdx.x;   // grid = 2 blocks -> k in [0,512)
    const float4* r = reinterpret_cast<const float4*>(w + (size_t)k * DIM);
    float s0 = 0.f, s1 = 0.f, s2 = 0.f, s3 = 0.f;
    #pragma unroll 8
    for (int q = 0; q < DIM / 4; ++q) {
        float4 v = r[q];
        s0 = fmaf(v.x, v.x, s0);
        s1 = fmaf(v.y, v.y, s1);
        s2 = fmaf(v.z, v.z, s2);
        s3 = fmaf(v.w, v.w, s3);
    }
    wsq[k] = (s0 + s1) + (s2 + s3);
    hist[k] = 0;
    if (k == 0) *mse_acc = 0.0;
}

// ---------------- main: argmin + quantized write + hist + mse ----------------
// 512 threads = 8 waves arranged 2 (point-groups) x 4 (code-groups).
// Wave tile: 128 pts x 64 codes. Lane tile: 16 pts x 8 codes.
// Code chunks of 256 (cch), D slices of 64 (dch) staged in LDS.
// NOTE: __launch_bounds__(512, 1) — LDS (153 KB) caps us at 1 block/CU anyway;
// asking for 2 waves/EU capped VGPRs at 128 and spilled ~80 regs (r3: VGPR=128,
// +40 MB scratch traffic each way, VALUBusy stuck at 52%).
__global__ __launch_bounds__(512, 1) void som_main(const float* __restrict__ x,
                                                   const float* __restrict__ w,
                                                   float* __restrict__ out,
                                                   const float* __restrict__ wsq,
                                                   int* __restrict__ hist,
                                                   double* __restrict__ mse_acc)
{
    __shared__ float xs[BM * LSTR];        // 69,632 B : x tile D-slice
    __shared__ float wst[256 * LSTR];      // 69,632 B : w chunk D-slice
    __shared__ float wsq_s[KC];            // 2 KB
    __shared__ float xsq_part[512];        // 2 KB : per (pt, half) |x|^2 partials
    __shared__ float red_d[4 * BM];        // 4 KB
    __shared__ int   red_i[4 * BM];        // 4 KB
    __shared__ int   bidx_s[BM];           // 1 KB
    __shared__ float wsum[4];

    const int tid  = threadIdx.x;
    const int ptBlock = blockIdx.x * BM;
    const int lane = tid & 63;
    const int wid  = tid >> 6;    // 0..7
    const int wgp  = wid >> 2;    // point group 0..1  (128 pts each)
    const int wgc  = wid & 3;     // code group 0..3   (64 codes each)
    const int lp   = lane >> 3;   // 0..7 point sub
    const int lc   = lane & 7;    // 0..7 code sub

    const float4* xg4 = reinterpret_cast<const float4*>(x);
    const float4* wg4 = reinterpret_cast<const float4*>(w);

    wsq_s[tid] = wsq[tid];        // 512 threads cover K=512

    float best[16];
    int   bidx[16];
    #pragma unroll
    for (int i = 0; i < 16; ++i) { best[i] = INFINITY; bidx[i] = 0; }

    float xacc = 0.f;             // |x|^2 partial for (pt=tid>>1, half=tid&1)

    const float* xbase = &xs[(wgp * 128 + lp) * LSTR];
    const float* wbase = &wst[(wgc * 64 + lc) * LSTR];

    for (int cch = 0; cch < 2; ++cch) {
        float acc[16][8];
        #pragma unroll
        for (int i = 0; i < 16; ++i)
            #pragma unroll
            for (int j = 0; j < 8; ++j) acc[i][j] = 0.f;

        for (int dch = 0; dch < 4; ++dch) {
            __syncthreads();      // readers of previous slice done
            // stage x slice: 256 rows x 16 float4
            #pragma unroll
            for (int it = 0; it < 8; ++it) {
                int idx = it * 512 + tid;          // 0..4095
                int row = idx >> 4, c4 = idx & 15;
                float4 v = xg4[(size_t)(ptBlock + row) * 64 + dch * 16 + c4];
                *reinterpret_cast<float4*>(&xs[row * LSTR + c4 * 4]) = v;
            }
            // stage w slice: 256 rows x 16 float4
            #pragma unroll
            for (int it = 0; it < 8; ++it) {
                int idx = it * 512 + tid;
                int row = idx >> 4, c4 = idx & 15;
                float4 v = wg4[(size_t)(cch * 256 + row) * 64 + dch * 16 + c4];
                *reinterpret_cast<float4*>(&wst[row * LSTR + c4 * 4]) = v;
            }
            __syncthreads();      // slice ready

            if (cch == 0) {       // accumulate |x|^2 from LDS (once per point)
                int pt = tid >> 1, half = tid & 1;
                const float* xr = &xs[pt * LSTR + half * 32];
                #pragma unroll
                for (int k = 0; k < 8; ++k) {
                    float4 v = *reinterpret_cast<const float4*>(xr + k * 4);
                    xacc = fmaf(v.x, v.x, xacc);
                    xacc = fmaf(v.y, v.y, xacc);
                    xacc = fmaf(v.z, v.z, xacc);
                    xacc = fmaf(v.w, v.w, xacc);
                }
            }

            // main FMA loop over this D slice
            for (int d4 = 0; d4 < DSL / 4; ++d4) {
                float4 wv[8];
                #pragma unroll
                for (int j = 0; j < 8; ++j)
                    wv[j] = *reinterpret_cast<const float4*>(wbase + j * 8 * LSTR + d4 * 4);
                #pragma unroll
                for (int i = 0; i < 16; ++i) {
                    float4 xv = *reinterpret_cast<const float4*>(xbase + i * 8 * LSTR + d4 * 4);
                    #pragma unroll
                    for (int j = 0; j < 8; ++j) {
                        acc[i][j] = fmaf(xv.x, wv[j].x, acc[i][j]);
                        acc[i][j] = fmaf(xv.y, wv[j].y, acc[i][j]);
                        acc[i][j] = fmaf(xv.z, wv[j].z, acc[i][j]);
                        acc[i][j] = fmaf(xv.w, wv[j].w, acc[i][j]);
                    }
                }
            }
        }

        // full-D dots done for this code chunk: dist = wsq[c] - 2*dot
        #pragma unroll
        for (int i = 0; i < 16; ++i)
            #pragma unroll
            for (int j = 0; j < 8; ++j) {
                int c = cch * 256 + wgc * 64 + j * 8 + lc;
                float dist = wsq_s[c] - 2.f * acc[i][j];
                if (dist < best[i]) { best[i] = dist; bidx[i] = c; }
            }
    }

    // store |x|^2 partials
    xsq_part[tid] = xacc;

    // reduce across lc lanes (low 3 bits)
    #pragma unroll
    for (int i = 0; i < 16; ++i) {
        #pragma unroll
        for (int m = 1; m <= 4; m <<= 1) {
            float od = __shfl_xor(best[i], m, 64);
            int   oi = __shfl_xor(bidx[i], m, 64);
            if (od < best[i] || (od == best[i] && oi < bidx[i])) { best[i] = od; bidx[i] = oi; }
        }
    }
    if (lc == 0) {
        #pragma unroll
        for (int i = 0; i < 16; ++i) {
            int p = wgp * 128 + i * 8 + lp;       // 0..255
            red_d[wgc * BM + p] = best[i];
            red_i[wgc * BM + p] = bidx[i];
        }
    }
    __syncthreads();

    // final per-point reduce over 4 code groups + mse
    if (tid < BM) {
        int p = tid;
        float bd = red_d[p];  int bi = red_i[p];
        #pragma unroll
        for (int g = 1; g < 4; ++g) {
            float d = red_d[g * BM + p];  int i2 = red_i[g * BM + p];
            if (d < bd || (d == bd && i2 < bi)) { bd = d; bi = i2; }
        }
        bidx_s[p] = bi;
        out[EOFF + ptBlock + p] = (float)bi;
        atomicAdd(&hist[bi], 1);

        float msum = xsq_part[2 * p] + xsq_part[2 * p + 1] + bd;  // |x-w|^2 for this point
        #pragma unroll
        for (int m = 32; m; m >>= 1) msum += __shfl_xor(msum, m, 64);
        if (lane == 0) wsum[wid] = msum;
    }
    __syncthreads();
    if (tid == 0)
        atomicAdd(mse_acc, (double)((wsum[0] + wsum[1]) + (wsum[2] + wsum[3])));

    // quantized = w[sel] write: 2 rows per iter, fully coalesced dword stores
    {
        int d = tid & 255;
        int ph = tid >> 8;        // 0..1
        for (int pp = 0; pp < 128; ++pp) {
            int p = pp * 2 + ph;
            int c = bidx_s[p];
            float qv = w[(size_t)c * DIM + d];
            out[QOFF + (size_t)(ptBlock + p) * DIM + d] = qv;
        }
    }
}

// ---------------- g[j] = sum_k bmat[j,k] * (wsq[k] + wsq[j] - 2 w_j.w_k) ----------------
__global__ __launch_bounds__(256) void som_g(const float* __restrict__ w,
                                             const float* __restrict__ bmat,
                                             const float* __restrict__ wsq,
                                             float* __restrict__ g)
{
    __shared__ float wj[DIM];
    __shared__ float psum[4];
    const int j = blockIdx.x;
    const int tid = threadIdx.x;
    wj[tid] = w[(size_t)j * DIM + tid];
    __syncthreads();
    const float wsqj = wsq[j];
    float sum = 0.f;
    for (int k = tid; k < KC; k += 256) {
        const float* wk = &w[(size_t)k * DIM];
        float d0 = 0.f, d1 = 0.f, d2 = 0.f, d3 = 0.f;
        #pragma unroll 4
        for (int d = 0; d < DIM; d += 4) {
            d0 = fmaf(wj[d + 0], wk[d + 0], d0);
            d1 = fmaf(wj[d + 1], wk[d + 1], d1);
            d2 = fmaf(wj[d + 2], wk[d + 2], d2);
            d3 = fmaf(wj[d + 3], wk[d + 3], d3);
        }
        float dot = (d0 + d1) + (d2 + d3);
        float t = wsq[k] + wsqj - 2.f * dot;
        sum = fmaf(bmat[(size_t)j * KC + k], t, sum);
    }
    #pragma unroll
    for (int m = 32; m; m >>= 1) sum += __shfl_xor(sum, m, 64);
    int lane = tid & 63, wid = tid >> 6;
    if (lane == 0) psum[wid] = sum;
    __syncthreads();
    if (tid == 0) g[j] = (psum[0] + psum[1]) + (psum[2] + psum[3]);
}

// ---------------- final: perplexity + loss ----------------
__global__ __launch_bounds__(512) void som_final(const int* __restrict__ hist,
                                                 const float* __restrict__ g,
                                                 const double* __restrict__ mse_acc,
                                                 float* __restrict__ out)
{
    __shared__ float e_part[8], k_part[8];
    const int tid = threadIdx.x;
    int cnt = hist[tid];
    float p = (float)cnt / (float)NPTS;
    float ent = -p * logf(p + 1e-10f);
    float koh = (float)cnt * g[tid];
    #pragma unroll
    for (int m = 32; m; m >>= 1) {
        ent += __shfl_xor(ent, m, 64);
        koh += __shfl_xor(koh, m, 64);
    }
    int lane = tid & 63, wid = tid >> 6;
    if (lane == 0) { e_part[wid] = ent; k_part[wid] = koh; }
    __syncthreads();
    if (tid == 0) {
        float es = 0.f, ks = 0.f;
        #pragma unroll
        for (int i = 0; i < 8; ++i) { es += e_part[i]; ks += k_part[i]; }
        float mse = (float)(*mse_acc / (double)(NPTS * (size_t)DIM));
        out[0] = fmaf(1.25f, mse, ks / (float)NPTS);
        out[PIDX] = expf(es);
    }
}

extern "C" void kernel_launch(void* const* d_in, const int* in_sizes, int n_in,
                              void* d_out, int out_size, void* d_ws, size_t ws_size,
                              hipStream_t stream) {
    const float* x    = (const float*)d_in[0];
    const float* w    = (const float*)d_in[1];
    const float* bmat = (const float*)d_in[2];
    float* out = (float*)d_out;

    float*  wsq  = (float*)d_ws;
    float*  g    = wsq + 512;
    int*    hist = (int*)d_ws + 1024;
    double* mse  = (double*)((char*)d_ws + 6144);

    som_prep <<<2, 256, 0, stream>>>(w, wsq, hist, mse);
    som_main <<<NBLK, 512, 0, stream>>>(x, w, out, wsq, hist, mse);
    som_g    <<<KC, 256, 0, stream>>>(w, bmat, wsq, g);
    som_final<<<1, KC, 0, stream>>>(hist, g, mse, out);
}

// Round 5
// 325.789 us; speedup vs baseline: 1.0642x; 1.0642x over previous
//
#include <hip/hip_runtime.h>
#include <hip/hip_bf16.h>
#include <hip/hip_fp16.h>
#include <math.h>

// Problem constants
#define NPTS 65536
#define DIM  256
#define KC   512

// som_main geometry (MFMA version)
#define BM    64                 // points per block
#define NBLK  (NPTS / BM)        // 1024 blocks
#define SLC   32                 // D-slice staged per step (one MFMA K=32)
#define FSTR  40                 // f16 LDS row stride (80 B, 16B-aligned, bank-spread)
#define EPS   0.05f              // exact-recheck margin (coarse err <~5e-4)

// d_out layout (floats): [0]=loss, [1..1+16777216)=quantized, [16777217]=perplexity,
// [16777218..+65536)=enc_idx (as float)
#define QOFF  1
#define PIDX  16777217
#define EOFF  16777218

typedef _Float16 h8   __attribute__((ext_vector_type(8)));
typedef _Float16 h4   __attribute__((ext_vector_type(4)));
typedef float    f32x4 __attribute__((ext_vector_type(4)));

// ---------------- prep: wsq[k] = |w_k|^2, zero hist + mse ----------------
__global__ __launch_bounds__(256) void som_prep(const float* __restrict__ w,
                                                float* __restrict__ wsq,
                                                int* __restrict__ hist,
                                                double* __restrict__ mse_acc)
{
    int k = blockIdx.x * 256 + threadIdx.x;
    const float4* r = reinterpret_cast<const float4*>(w + (size_t)k * DIM);
    float s0 = 0.f, s1 = 0.f, s2 = 0.f, s3 = 0.f;
    #pragma unroll 8
    for (int q = 0; q < DIM / 4; ++q) {
        float4 v = r[q];
        s0 = fmaf(v.x, v.x, s0);
        s1 = fmaf(v.y, v.y, s1);
        s2 = fmaf(v.z, v.z, s2);
        s3 = fmaf(v.w, v.w, s3);
    }
    wsq[k] = (s0 + s1) + (s2 + s3);
    hist[k] = 0;
    if (k == 0) *mse_acc = 0.0;
}

// split a float4 into hi/lo fp16 quads
__device__ inline void cvt_split4(float4 v, h4& hv, h4& lv) {
    _Float16 h0 = (_Float16)v.x, h1 = (_Float16)v.y, h2 = (_Float16)v.z, h3 = (_Float16)v.w;
    hv[0] = h0; hv[1] = h1; hv[2] = h2; hv[3] = h3;
    lv[0] = (_Float16)(v.x - (float)h0);
    lv[1] = (_Float16)(v.y - (float)h1);
    lv[2] = (_Float16)(v.z - (float)h2);
    lv[3] = (_Float16)(v.w - (float)h3);
}

// merge top-2 set (b2,i2 secondary) with another top-2 set; first-index tie-break on best
__device__ inline void merge_top2(float& b1, int& i1, float& b2, int& i2,
                                  float ob1, int oi1, float ob2, int oi2) {
    bool ow = (ob1 < b1) || (ob1 == b1 && oi1 < i1);
    float lb = ow ? b1 : ob1; int li = ow ? i1 : oi1;   // losing best -> second candidate
    if (ow) { b1 = ob1; i1 = oi1; }
    float c2 = b2; int ci = i2;
    if (ob2 < c2 || (ob2 == c2 && oi2 < ci)) { c2 = ob2; ci = oi2; }
    if (lb  < c2 || (lb  == c2 && li  < ci)) { c2 = lb;  ci = li;  }
    b2 = c2; i2 = ci;
}

// exact fp32 distance (same accumulation family as the r3-passing kernel)
__device__ inline float exact_dist(const float* __restrict__ xr,
                                   const float* __restrict__ w, int c, float wsqc) {
    const float* wr = w + (size_t)c * DIM;
    float d0 = 0.f, d1 = 0.f, d2 = 0.f, d3 = 0.f;
    #pragma unroll 4
    for (int d = 0; d < DIM; d += 4) {
        d0 = fmaf(xr[d + 0], wr[d + 0], d0);
        d1 = fmaf(xr[d + 1], wr[d + 1], d1);
        d2 = fmaf(xr[d + 2], wr[d + 2], d2);
        d3 = fmaf(xr[d + 3], wr[d + 3], d3);
    }
    return wsqc - 2.f * ((d0 + d1) + (d2 + d3));
}

// ---------------- main: split-fp16 MFMA argmin + top-2 exact recheck ----------------
// 256 threads = 4 waves; each wave = one 64-code group. Block tile 64 pts x 512 codes
// (2 chunks of 256). Wave tile 64 pts x 64 codes = 4x4 C-frags (16x16x32 f16 MFMA).
// dot = xh*wh + xh*wl + xl*wh ; dropped lo*lo ~<5e-4 ; any gap < EPS re-verified in fp32.
__global__ __launch_bounds__(256) void som_main(const float* __restrict__ x,
                                                const float* __restrict__ w,
                                                float* __restrict__ out,
                                                const float* __restrict__ wsq,
                                                int* __restrict__ hist,
                                                double* __restrict__ mse_acc)
{
    __shared__ _Float16 xh[BM * FSTR], xl[BM * FSTR];       // 5,120 B each
    __shared__ _Float16 wh[256 * FSTR], wl[256 * FSTR];     // 20,480 B each
    __shared__ float wsq_s[KC];                             // 2 KB
    __shared__ float red_b[4][BM], red_s[4][BM];            // 2 KB
    __shared__ int   red_ib[4][BM], red_is[4][BM];          // 2 KB
    __shared__ int   bidx_s[BM];
    __shared__ float wsum[4];

    const int tid  = threadIdx.x;
    const int lane = tid & 63;
    const int wid  = tid >> 6;        // code group 0..3 (64 codes)
    const int l15  = lane & 15;
    const int kg   = lane >> 4;       // 0..3 k-chunk group
    const int ptBlock = blockIdx.x * BM;

    wsq_s[tid] = wsq[tid];
    wsq_s[256 + tid] = wsq[256 + tid];

    const float4* xg4 = reinterpret_cast<const float4*>(x);
    const float4* wg4 = reinterpret_cast<const float4*>(w);

    // running top-2 state: this lane owns point p = (l15>>2)*16 + kg*4 + (l15&3)
    float sb = INFINITY, ss = INFINITY;
    int   ib = 0, is2 = 0;

    for (int cch = 0; cch < 2; ++cch) {
        f32x4 acc[4][4];
        #pragma unroll
        for (int rt = 0; rt < 4; ++rt)
            #pragma unroll
            for (int ct = 0; ct < 4; ++ct)
                acc[rt][ct] = (f32x4){0.f, 0.f, 0.f, 0.f};

        for (int dsl = 0; dsl < 8; ++dsl) {
            __syncthreads();          // previous slice consumed
            // stage x slice: 64 rows x 8 float4
            #pragma unroll
            for (int it = 0; it < 2; ++it) {
                int idx = it * 256 + tid;
                int row = idx >> 3, c4 = idx & 7;
                float4 v = xg4[(size_t)(ptBlock + row) * 64 + dsl * 8 + c4];
                h4 hv, lv; cvt_split4(v, hv, lv);
                *reinterpret_cast<h4*>(&xh[row * FSTR + c4 * 4]) = hv;
                *reinterpret_cast<h4*>(&xl[row * FSTR + c4 * 4]) = lv;
            }
            // stage w slice: 256 rows x 8 float4 (L2-hot re-reads)
            #pragma unroll
            for (int it = 0; it < 8; ++it) {
                int idx = it * 256 + tid;
                int row = idx >> 3, c4 = idx & 7;
                float4 v = wg4[(size_t)(cch * 256 + row) * 64 + dsl * 8 + c4];
                h4 hv, lv; cvt_split4(v, hv, lv);
                *reinterpret_cast<h4*>(&wh[row * FSTR + c4 * 4]) = hv;
                *reinterpret_cast<h4*>(&wl[row * FSTR + c4 * 4]) = lv;
            }
            __syncthreads();          // slice ready

            // A fragments (points), hoisted: row = rt*16 + l15, k-chunk = kg*8
            h8 Ah[4], Al[4];
            #pragma unroll
            for (int rt = 0; rt < 4; ++rt) {
                int ro = (rt * 16 + l15) * FSTR + kg * 8;
                Ah[rt] = *reinterpret_cast<const h8*>(&xh[ro]);
                Al[rt] = *reinterpret_cast<const h8*>(&xl[ro]);
            }
            #pragma unroll
            for (int ct = 0; ct < 4; ++ct) {
                int co = (wid * 64 + ct * 16 + l15) * FSTR + kg * 8;
                h8 Bh = *reinterpret_cast<const h8*>(&wh[co]);
                h8 Bl = *reinterpret_cast<const h8*>(&wl[co]);
                #pragma unroll
                for (int rt = 0; rt < 4; ++rt) {
                    acc[rt][ct] = __builtin_amdgcn_mfma_f32_16x16x32_f16(Ah[rt], Bh, acc[rt][ct], 0, 0, 0);
                    acc[rt][ct] = __builtin_amdgcn_mfma_f32_16x16x32_f16(Al[rt], Bh, acc[rt][ct], 0, 0, 0);
                    acc[rt][ct] = __builtin_amdgcn_mfma_f32_16x16x32_f16(Ah[rt], Bl, acc[rt][ct], 0, 0, 0);
                }
            }
        }

        // per-chunk epilogue: dist = wsq - 2*dot; per-point top2 over this chunk
        #pragma unroll
        for (int rt = 0; rt < 4; ++rt) {
            #pragma unroll
            for (int r = 0; r < 4; ++r) {
                int c0 = cch * 256 + wid * 64 + l15;
                float b1 = wsq_s[c0] - 2.f * acc[rt][0][r];
                int   i1 = c0;
                float b2 = INFINITY; int i2 = i1;
                #pragma unroll
                for (int ct = 1; ct < 4; ++ct) {
                    int c = c0 + ct * 16;
                    float d = wsq_s[c] - 2.f * acc[rt][ct][r];
                    if (d < b1 || (d == b1 && c < i1)) { b2 = b1; i2 = i1; b1 = d; i1 = c; }
                    else if (d < b2) { b2 = d; i2 = c; }
                }
                // butterfly across the 16 lanes of this kg-group (masks 1,2,4,8)
                #pragma unroll
                for (int m = 1; m <= 8; m <<= 1) {
                    float ob1 = __shfl_xor(b1, m, 64), ob2 = __shfl_xor(b2, m, 64);
                    int   oi1 = __shfl_xor(i1, m, 64), oi2 = __shfl_xor(i2, m, 64);
                    merge_top2(b1, i1, b2, i2, ob1, oi1, ob2, oi2);
                }
                if (l15 == rt * 4 + r)
                    merge_top2(sb, ib, ss, is2, b1, i1, b2, i2);
            }
        }
    }

    // cross-wave merge via LDS
    int myp = (l15 >> 2) * 16 + kg * 4 + (l15 & 3);
    red_b[wid][myp] = sb;  red_s[wid][myp] = ss;
    red_ib[wid][myp] = ib; red_is[wid][myp] = is2;
    __syncthreads();

    if (tid < BM) {
        float b = red_b[0][tid], s = red_s[0][tid];
        int  bi = red_ib[0][tid], si = red_is[0][tid];
        #pragma unroll
        for (int g = 1; g < 4; ++g)
            merge_top2(b, bi, s, si, red_b[g][tid], red_ib[g][tid], red_s[g][tid], red_is[g][tid]);

        if (s - b < EPS) {   // near-tie: resolve in exact fp32 (rare, ~1%)
            const float* xr = x + (size_t)(ptBlock + tid) * DIM;
            float d1 = exact_dist(xr, w, bi, wsq_s[bi]);
            float d2 = exact_dist(xr, w, si, wsq_s[si]);
            if (d2 < d1 || (d2 == d1 && si < bi)) bi = si;
        }
        bidx_s[tid] = bi;
        out[EOFF + ptBlock + tid] = (float)bi;
        atomicAdd(&hist[bi], 1);
    }
    __syncthreads();

    // quantized write + exact fp32 mse (x re-read is L2-hot)
    float lsum = 0.f;
    for (int p = 0; p < BM; ++p) {
        int c = bidx_s[p];
        float qv = w[(size_t)c * DIM + tid];
        float xv = x[(size_t)(ptBlock + p) * DIM + tid];
        out[QOFF + (size_t)(ptBlock + p) * DIM + tid] = qv;
        float dd = qv - xv;
        lsum = fmaf(dd, dd, lsum);
    }
    #pragma unroll
    for (int m = 32; m; m >>= 1) lsum += __shfl_xor(lsum, m, 64);
    if (lane == 0) wsum[wid] = lsum;
    __syncthreads();
    if (tid == 0)
        atomicAdd(mse_acc, (double)((wsum[0] + wsum[1]) + (wsum[2] + wsum[3])));
}

// ---------------- g[j] = sum_k bmat[j,k] * (wsq[k] + wsq[j] - 2 w_j.w_k) ----------------
__global__ __launch_bounds__(256) void som_g(const float* __restrict__ w,
                                             const float* __restrict__ bmat,
                                             const float* __restrict__ wsq,
                                             float* __restrict__ g)
{
    __shared__ float wj[DIM];
    __shared__ float psum[4];
    const int j = blockIdx.x;
    const int tid = threadIdx.x;
    wj[tid] = w[(size_t)j * DIM + tid];
    __syncthreads();
    const float wsqj = wsq[j];
    float sum = 0.f;
    for (int k = tid; k < KC; k += 256) {
        const float* wk = &w[(size_t)k * DIM];
        float d0 = 0.f, d1 = 0.f, d2 = 0.f, d3 = 0.f;
        #pragma unroll 4
        for (int d = 0; d < DIM; d += 4) {
            d0 = fmaf(wj[d + 0], wk[d + 0], d0);
            d1 = fmaf(wj[d + 1], wk[d + 1], d1);
            d2 = fmaf(wj[d + 2], wk[d + 2], d2);
            d3 = fmaf(wj[d + 3], wk[d + 3], d3);
        }
        float dot = (d0 + d1) + (d2 + d3);
        float t = wsq[k] + wsqj - 2.f * dot;
        sum = fmaf(bmat[(size_t)j * KC + k], t, sum);
    }
    #pragma unroll
    for (int m = 32; m; m >>= 1) sum += __shfl_xor(sum, m, 64);
    int lane = tid & 63, wid = tid >> 6;
    if (lane == 0) psum[wid] = sum;
    __syncthreads();
    if (tid == 0) g[j] = (psum[0] + psum[1]) + (psum[2] + psum[3]);
}

// ---------------- final: perplexity + loss ----------------
__global__ __launch_bounds__(512) void som_final(const int* __restrict__ hist,
                                                 const float* __restrict__ g,
                                                 const double* __restrict__ mse_acc,
                                                 float* __restrict__ out)
{
    __shared__ float e_part[8], k_part[8];
    const int tid = threadIdx.x;
    int cnt = hist[tid];
    float p = (float)cnt / (float)NPTS;
    float ent = -p * logf(p + 1e-10f);
    float koh = (float)cnt * g[tid];
    #pragma unroll
    for (int m = 32; m; m >>= 1) {
        ent += __shfl_xor(ent, m, 64);
        koh += __shfl_xor(koh, m, 64);
    }
    int lane = tid & 63, wid = tid >> 6;
    if (lane == 0) { e_part[wid] = ent; k_part[wid] = koh; }
    __syncthreads();
    if (tid == 0) {
        float es = 0.f, ks = 0.f;
        #pragma unroll
        for (int i = 0; i < 8; ++i) { es += e_part[i]; ks += k_part[i]; }
        float mse = (float)(*mse_acc / (double)(NPTS * (size_t)DIM));
        out[0] = fmaf(1.25f, mse, ks / (float)NPTS);
        out[PIDX] = expf(es);
    }
}

extern "C" void kernel_launch(void* const* d_in, const int* in_sizes, int n_in,
                              void* d_out, int out_size, void* d_ws, size_t ws_size,
                              hipStream_t stream) {
    const float* x    = (const float*)d_in[0];
    const float* w    = (const float*)d_in[1];
    const float* bmat = (const float*)d_in[2];
    float* out = (float*)d_out;

    float*  wsq  = (float*)d_ws;
    float*  g    = wsq + 512;
    int*    hist = (int*)d_ws + 1024;
    double* mse  = (double*)((char*)d_ws + 6144);

    som_prep <<<2, 256, 0, stream>>>(w, wsq, hist, mse);
    som_main <<<NBLK, 256, 0, stream>>>(x, w, out, wsq, hist, mse);
    som_g    <<<KC, 256, 0, stream>>>(w, bmat, wsq, g);
    som_final<<<1, KC, 0, stream>>>(hist, g, mse, out);
}

// Round 6
// 193.465 us; speedup vs baseline: 1.7920x; 1.6840x over previous
//
#include <hip/hip_runtime.h>
#include <hip/hip_bf16.h>
#include <hip/hip_fp16.h>
#include <math.h>

// Problem constants
#define NPTS 65536
#define DIM  256
#define KC   512

// som_main geometry
#define BM    64                  // points per block
#define NBLK  (NPTS / BM)         // 1024 blocks
#define XSTR  264                 // x LDS row stride in halfs (528 B: 16B-aligned, uniform banks)
#define EPS   0.05f               // exact-recheck margin (coarse err ~<5e-4)

// d_out layout (floats): [0]=loss, [1..1+16777216)=quantized, [16777217]=perplexity,
// [16777218..+65536)=enc_idx (as float)
#define QOFF  1
#define PIDX  16777217
#define EOFF  16777218

// d_ws layout:
//   wfh  _Float16[131072]  @ 0        (256 KB)  w hi, MFMA fragment order
//   wfl  _Float16[131072]  @ 262144   (256 KB)  w lo
//   wsq  float[512]        @ 524288
//   g    float[512]        @ 526336
//   hist int[512]          @ 528384
//   mse  double            @ 530432
// fragment order: off(c,k) = ((((c>>4)*8 + (k>>5))*4 + ((k>>3)&3))*128) + (c&15)*8 + (k&7)

typedef _Float16 h8    __attribute__((ext_vector_type(8)));
typedef float    f32x4 __attribute__((ext_vector_type(4)));

__device__ inline void cvt_split8(float4 a, float4 b, h8& hv, h8& lv) {
    float f[8] = {a.x, a.y, a.z, a.w, b.x, b.y, b.z, b.w};
    #pragma unroll
    for (int i = 0; i < 8; ++i) {
        _Float16 h = (_Float16)f[i];
        hv[i] = h;
        lv[i] = (_Float16)(f[i] - (float)h);
    }
}

// merge top-2 set with another top-2 set; first-index tie-break on best (r5-verified)
__device__ inline void merge_top2(float& b1, int& i1, float& b2, int& i2,
                                  float ob1, int oi1, float ob2, int oi2) {
    bool ow = (ob1 < b1) || (ob1 == b1 && oi1 < i1);
    float lb = ow ? b1 : ob1; int li = ow ? i1 : oi1;
    if (ow) { b1 = ob1; i1 = oi1; }
    float c2 = b2; int ci = i2;
    if (ob2 < c2 || (ob2 == c2 && oi2 < ci)) { c2 = ob2; ci = oi2; }
    if (lb  < c2 || (lb  == c2 && li  < ci)) { c2 = lb;  ci = li;  }
    b2 = c2; i2 = ci;
}

// exact fp32 distance (same accumulation family as the r3-passing kernel)
__device__ inline float exact_dist(const float* __restrict__ xr,
                                   const float* __restrict__ w, int c, float wsqc) {
    const float* wr = w + (size_t)c * DIM;
    float d0 = 0.f, d1 = 0.f, d2 = 0.f, d3 = 0.f;
    #pragma unroll 4
    for (int d = 0; d < DIM; d += 4) {
        d0 = fmaf(xr[d + 0], wr[d + 0], d0);
        d1 = fmaf(xr[d + 1], wr[d + 1], d1);
        d2 = fmaf(xr[d + 2], wr[d + 2], d2);
        d3 = fmaf(xr[d + 3], wr[d + 3], d3);
    }
    return wsqc - 2.f * ((d0 + d1) + (d2 + d3));
}

// ---------------- prep: wsq + split-f16 conversion of w into fragment order ----------------
__global__ __launch_bounds__(256) void som_prep(const float* __restrict__ w,
                                                _Float16* __restrict__ wfh,
                                                _Float16* __restrict__ wfl,
                                                float* __restrict__ wsq,
                                                int* __restrict__ hist,
                                                double* __restrict__ mse_acc)
{
    int c = blockIdx.x * 256 + threadIdx.x;   // code row, grid = 2 blocks
    const float4* r = reinterpret_cast<const float4*>(w + (size_t)c * DIM);

    // wsq in the exact r3/r5 accumulation order
    float s0 = 0.f, s1 = 0.f, s2 = 0.f, s3 = 0.f;
    #pragma unroll 8
    for (int q = 0; q < DIM / 4; ++q) {
        float4 v = r[q];
        s0 = fmaf(v.x, v.x, s0);
        s1 = fmaf(v.y, v.y, s1);
        s2 = fmaf(v.z, v.z, s2);
        s3 = fmaf(v.w, v.w, s3);
    }
    wsq[c] = (s0 + s1) + (s2 + s3);
    hist[c] = 0;
    if (c == 0) *mse_acc = 0.0;

    // split-convert into fragment order: g-th group of 8 k's
    int ctg = c >> 4, l15 = c & 15;
    #pragma unroll 4
    for (int g = 0; g < 32; ++g) {
        float4 a = r[g * 2], b = r[g * 2 + 1];
        h8 hv, lv; cvt_split8(a, b, hv, lv);
        int dsl = g >> 2, kg = g & 3;
        size_t off = (((size_t)(ctg * 8 + dsl)) * 4 + kg) * 128 + l15 * 8;
        *reinterpret_cast<h8*>(wfh + off) = hv;
        *reinterpret_cast<h8*>(wfl + off) = lv;
    }
}

// ---------------- main: swapped-operand split-fp16 MFMA argmin ----------------
// 256 threads = 4 waves. Block = 64 pts x all 512 codes. Wave wid owns codes
// [wid*128, wid*128+128) = 8 code-tiles of 16, in 2 passes of 4 tiles.
// C[code][pt] = mfma(w_frag, x_frag): lane (kg,l15) holds codes kg*4+reg of each
// tile for point col l15 -> top-2 reduction is in-lane, cross-lane only masks 16/32.
__global__ __launch_bounds__(256) void som_main(const float* __restrict__ x,
                                                const float* __restrict__ w,
                                                const _Float16* __restrict__ wfh,
                                                const _Float16* __restrict__ wfl,
                                                float* __restrict__ out,
                                                const float* __restrict__ wsq,
                                                int* __restrict__ hist,
                                                double* __restrict__ mse_acc)
{
    alignas(16) __shared__ _Float16 xh[BM * XSTR];   // 33,792 B
    alignas(16) __shared__ _Float16 xl[BM * XSTR];   // 33,792 B
    __shared__ float wsq_s[KC];                      // 2 KB
    __shared__ float red_b[4][BM], red_s[4][BM];     // 2 KB
    __shared__ int   red_ib[4][BM], red_is[4][BM];   // 2 KB
    __shared__ int   bidx_s[BM];
    __shared__ float wsum[4];

    const int tid  = threadIdx.x;
    const int lane = tid & 63;
    const int wid  = tid >> 6;        // wave: code group of 128
    const int l15  = lane & 15;       // point col within tile / frag row
    const int kg   = lane >> 4;       // k-group 0..3 (and C row group)
    const int ptBlock = blockIdx.x * BM;

    // ---- stage x tile once: split to f16 hi/lo in LDS ----
    const float4* xg4 = reinterpret_cast<const float4*>(x);
    #pragma unroll
    for (int it = 0; it < 8; ++it) {
        int u = it * 256 + tid;       // h8 unit: 64 rows x 32 groups
        int row = u >> 5, c8 = u & 31;
        float4 a = xg4[(size_t)(ptBlock + row) * 64 + c8 * 2];
        float4 b = xg4[(size_t)(ptBlock + row) * 64 + c8 * 2 + 1];
        h8 hv, lv; cvt_split8(a, b, hv, lv);
        *reinterpret_cast<h8*>(&xh[row * XSTR + c8 * 8]) = hv;
        *reinterpret_cast<h8*>(&xl[row * XSTR + c8 * 8]) = lv;
    }
    wsq_s[tid] = wsq[tid];
    wsq_s[256 + tid] = wsq[256 + tid];
    __syncthreads();                  // the only barrier before epilogue

    // per-lane top-2 state for point col = ct*16 + l15 (4 points per lane)
    float sb[4], ss[4];
    int   ib[4], is2[4];
    #pragma unroll
    for (int ct = 0; ct < 4; ++ct) { sb[ct] = INFINITY; ss[ct] = INFINITY; ib[ct] = 0; is2[ct] = 0; }

    const int codeBase = wid * 128;

    #pragma unroll 1
    for (int pass = 0; pass < 2; ++pass) {
        f32x4 acc[4][4];              // [rt (code tile)][ct (point tile)]
        #pragma unroll
        for (int rt = 0; rt < 4; ++rt)
            #pragma unroll
            for (int ct = 0; ct < 4; ++ct)
                acc[rt][ct] = (f32x4){0.f, 0.f, 0.f, 0.f};

        #pragma unroll 1
        for (int dsl = 0; dsl < 8; ++dsl) {
            // x fragments (B operand) from LDS: row = ct*16+l15, k = dsl*32+kg*8
            h8 Bh[4], Bl[4];
            #pragma unroll
            for (int ct = 0; ct < 4; ++ct) {
                int off = (ct * 16 + l15) * XSTR + dsl * 32 + kg * 8;
                Bh[ct] = *reinterpret_cast<const h8*>(&xh[off]);
                Bl[ct] = *reinterpret_cast<const h8*>(&xl[off]);
            }
            // w fragments (A operand) straight from global (L2-resident, coalesced 1KB/wave)
            #pragma unroll
            for (int rt = 0; rt < 4; ++rt) {
                int ctg = (codeBase >> 4) + pass * 4 + rt;
                size_t off = (((size_t)ctg * 8 + dsl) * 4 + kg) * 128 + l15 * 8;
                h8 Ah = *reinterpret_cast<const h8*>(wfh + off);
                h8 Al = *reinterpret_cast<const h8*>(wfl + off);
                #pragma unroll
                for (int ct = 0; ct < 4; ++ct) {
                    acc[rt][ct] = __builtin_amdgcn_mfma_f32_16x16x32_f16(Ah, Bh[ct], acc[rt][ct], 0, 0, 0);
                    acc[rt][ct] = __builtin_amdgcn_mfma_f32_16x16x32_f16(Al, Bh[ct], acc[rt][ct], 0, 0, 0);
                    acc[rt][ct] = __builtin_amdgcn_mfma_f32_16x16x32_f16(Ah, Bl[ct], acc[rt][ct], 0, 0, 0);
                }
            }
        }

        // in-lane top-2 scan: codes ascend in (pass, rt, r) for this lane's kg
        #pragma unroll
        for (int rt = 0; rt < 4; ++rt) {
            int cbase = codeBase + pass * 64 + rt * 16 + kg * 4;
            #pragma unroll
            for (int ct = 0; ct < 4; ++ct) {
                #pragma unroll
                for (int r = 0; r < 4; ++r) {
                    int c = cbase + r;
                    float d = wsq_s[c] - 2.f * acc[rt][ct][r];
                    if (d < sb[ct] || (d == sb[ct] && c < ib[ct])) {
                        ss[ct] = sb[ct]; is2[ct] = ib[ct]; sb[ct] = d; ib[ct] = c;
                    } else if (d < ss[ct] || (d == ss[ct] && c < is2[ct])) {
                        ss[ct] = d; is2[ct] = c;
                    }
                }
            }
        }
    }

    // cross-lane merge over kg groups only: masks 16, 32
    #pragma unroll
    for (int ct = 0; ct < 4; ++ct) {
        #pragma unroll
        for (int m = 16; m <= 32; m <<= 1) {
            float ob1 = __shfl_xor(sb[ct], m, 64), ob2 = __shfl_xor(ss[ct], m, 64);
            int   oi1 = __shfl_xor(ib[ct], m, 64), oi2 = __shfl_xor(is2[ct], m, 64);
            merge_top2(sb[ct], ib[ct], ss[ct], is2[ct], ob1, oi1, ob2, oi2);
        }
    }
    if (kg == 0) {
        #pragma unroll
        for (int ct = 0; ct < 4; ++ct) {
            int p = ct * 16 + l15;
            red_b[wid][p] = sb[ct];  red_s[wid][p] = ss[ct];
            red_ib[wid][p] = ib[ct]; red_is[wid][p] = is2[ct];
        }
    }
    __syncthreads();

    // cross-wave merge + exact recheck + enc_idx + hist (r5-verified)
    if (tid < BM) {
        float b = red_b[0][tid], s = red_s[0][tid];
        int  bi = red_ib[0][tid], si = red_is[0][tid];
        #pragma unroll
        for (int g = 1; g < 4; ++g)
            merge_top2(b, bi, s, si, red_b[g][tid], red_ib[g][tid], red_s[g][tid], red_is[g][tid]);

        if (s - b < EPS) {            // near-tie: resolve in exact fp32 (rare)
            const float* xr = x + (size_t)(ptBlock + tid) * DIM;
            float d1 = exact_dist(xr, w, bi, wsq_s[bi]);
            float d2 = exact_dist(xr, w, si, wsq_s[si]);
            if (d2 < d1 || (d2 == d1 && si < bi)) bi = si;
        }
        bidx_s[tid] = bi;
        out[EOFF + ptBlock + tid] = (float)bi;
        atomicAdd(&hist[bi], 1);
    }
    __syncthreads();

    // quantized write + exact fp32 mse (x re-read L2-hot)
    float lsum = 0.f;
    for (int p = 0; p < BM; ++p) {
        int c = bidx_s[p];
        float qv = w[(size_t)c * DIM + tid];
        float xv = x[(size_t)(ptBlock + p) * DIM + tid];
        out[QOFF + (size_t)(ptBlock + p) * DIM + tid] = qv;
        float dd = qv - xv;
        lsum = fmaf(dd, dd, lsum);
    }
    #pragma unroll
    for (int m = 32; m; m >>= 1) lsum += __shfl_xor(lsum, m, 64);
    if (lane == 0) wsum[wid] = lsum;
    __syncthreads();
    if (tid == 0)
        atomicAdd(mse_acc, (double)((wsum[0] + wsum[1]) + (wsum[2] + wsum[3])));
}

// ---------------- g[j] = sum_k bmat[j,k] * (wsq[k] + wsq[j] - 2 w_j.w_k) ----------------
__global__ __launch_bounds__(256) void som_g(const float* __restrict__ w,
                                             const float* __restrict__ bmat,
                                             const float* __restrict__ wsq,
                                             float* __restrict__ g)
{
    __shared__ float wj[DIM];
    __shared__ float psum[4];
    const int j = blockIdx.x;
    const int tid = threadIdx.x;
    wj[tid] = w[(size_t)j * DIM + tid];
    __syncthreads();
    const float wsqj = wsq[j];
    float sum = 0.f;
    for (int k = tid; k < KC; k += 256) {
        const float* wk = &w[(size_t)k * DIM];
        float d0 = 0.f, d1 = 0.f, d2 = 0.f, d3 = 0.f;
        #pragma unroll 4
        for (int d = 0; d < DIM; d += 4) {
            d0 = fmaf(wj[d + 0], wk[d + 0], d0);
            d1 = fmaf(wj[d + 1], wk[d + 1], d1);
            d2 = fmaf(wj[d + 2], wk[d + 2], d2);
            d3 = fmaf(wj[d + 3], wk[d + 3], d3);
        }
        float dot = (d0 + d1) + (d2 + d3);
        float t = wsq[k] + wsqj - 2.f * dot;
        sum = fmaf(bmat[(size_t)j * KC + k], t, sum);
    }
    #pragma unroll
    for (int m = 32; m; m >>= 1) sum += __shfl_xor(sum, m, 64);
    int lane = tid & 63, wid = tid >> 6;
    if (lane == 0) psum[wid] = sum;
    __syncthreads();
    if (tid == 0) g[j] = (psum[0] + psum[1]) + (psum[2] + psum[3]);
}

// ---------------- final: perplexity + loss ----------------
__global__ __launch_bounds__(512) void som_final(const int* __restrict__ hist,
                                                 const float* __restrict__ g,
                                                 const double* __restrict__ mse_acc,
                                                 float* __restrict__ out)
{
    __shared__ float e_part[8], k_part[8];
    const int tid = threadIdx.x;
    int cnt = hist[tid];
    float p = (float)cnt / (float)NPTS;
    float ent = -p * logf(p + 1e-10f);
    float koh = (float)cnt * g[tid];
    #pragma unroll
    for (int m = 32; m; m >>= 1) {
        ent += __shfl_xor(ent, m, 64);
        koh += __shfl_xor(koh, m, 64);
    }
    int lane = tid & 63, wid = tid >> 6;
    if (lane == 0) { e_part[wid] = ent; k_part[wid] = koh; }
    __syncthreads();
    if (tid == 0) {
        float es = 0.f, ks = 0.f;
        #pragma unroll
        for (int i = 0; i < 8; ++i) { es += e_part[i]; ks += k_part[i]; }
        float mse = (float)(*mse_acc / (double)(NPTS * (size_t)DIM));
        out[0] = fmaf(1.25f, mse, ks / (float)NPTS);
        out[PIDX] = expf(es);
    }
}

extern "C" void kernel_launch(void* const* d_in, const int* in_sizes, int n_in,
                              void* d_out, int out_size, void* d_ws, size_t ws_size,
                              hipStream_t stream) {
    const float* x    = (const float*)d_in[0];
    const float* w    = (const float*)d_in[1];
    const float* bmat = (const float*)d_in[2];
    float* out = (float*)d_out;

    _Float16* wfh = (_Float16*)d_ws;                         // 256 KB
    _Float16* wfl = wfh + 131072;                            // 256 KB
    float*  wsq  = (float*)((char*)d_ws + 524288);
    float*  g    = (float*)((char*)d_ws + 526336);
    int*    hist = (int*)((char*)d_ws + 528384);
    double* mse  = (double*)((char*)d_ws + 530432);

    som_prep <<<2, 256, 0, stream>>>(w, wfh, wfl, wsq, hist, mse);
    som_main <<<NBLK, 256, 0, stream>>>(x, w, wfh, wfl, out, wsq, hist, mse);
    som_g    <<<KC, 256, 0, stream>>>(w, bmat, wsq, g);
    som_final<<<1, KC, 0, stream>>>(hist, g, mse, out);
}

// Round 7
// 163.164 us; speedup vs baseline: 2.1248x; 1.1857x over previous
//
#include <hip/hip_runtime.h>
#include <hip/hip_bf16.h>
#include <hip/hip_fp16.h>
#include <math.h>

// Problem constants
#define NPTS 65536
#define DIM  256
#define KC   512

// som_main geometry
#define BM    64                  // points per block
#define NBLK  (NPTS / BM)         // 1024 blocks
#define XSTR  264                 // x LDS row stride in halfs (528 B: 16B-aligned)
#define EPS   0.01f               // exact-recheck margin (coarse err ~<2e-5)

// d_out layout (floats): [0]=loss, [1..1+16777216)=quantized, [16777217]=perplexity,
// [16777218..+65536)=enc_idx (as float)
#define QOFF  1
#define PIDX  16777217
#define EOFF  16777218

// d_ws layout:
//   wfh  _Float16[131072]  @ 0        (256 KB)  w hi, MFMA fragment order
//   wfl  _Float16[131072]  @ 262144   (256 KB)  w lo
//   wsq  float[512]        @ 524288
//   g    float[512]        @ 526336
//   hist int[512]          @ 528384
//   mse  double            @ 530432
// fragment order: off(c,k) = ((((c>>4)*8 + (k>>5))*4 + ((k>>3)&3))*128) + (c&15)*8 + (k&7)

typedef _Float16 h8    __attribute__((ext_vector_type(8)));
typedef float    f32x4 __attribute__((ext_vector_type(4)));

__device__ inline void cvt_split8(float4 a, float4 b, h8& hv, h8& lv) {
    float f[8] = {a.x, a.y, a.z, a.w, b.x, b.y, b.z, b.w};
    #pragma unroll
    for (int i = 0; i < 8; ++i) {
        _Float16 h = (_Float16)f[i];
        hv[i] = h;
        lv[i] = (_Float16)(f[i] - (float)h);
    }
}

// merge top-2 set with another top-2 set; first-index tie-break on best (r5-verified)
__device__ inline void merge_top2(float& b1, int& i1, float& b2, int& i2,
                                  float ob1, int oi1, float ob2, int oi2) {
    bool ow = (ob1 < b1) || (ob1 == b1 && oi1 < i1);
    float lb = ow ? b1 : ob1; int li = ow ? i1 : oi1;
    if (ow) { b1 = ob1; i1 = oi1; }
    float c2 = b2; int ci = i2;
    if (ob2 < c2 || (ob2 == c2 && oi2 < ci)) { c2 = ob2; ci = oi2; }
    if (lb  < c2 || (lb  == c2 && li  < ci)) { c2 = lb;  ci = li;  }
    b2 = c2; i2 = ci;
}

// exact fp32 distance (same accumulation family as the r3-passing kernel)
__device__ inline float exact_dist(const float* __restrict__ xr,
                                   const float* __restrict__ w, int c, float wsqc) {
    const float* wr = w + (size_t)c * DIM;
    float d0 = 0.f, d1 = 0.f, d2 = 0.f, d3 = 0.f;
    #pragma unroll 4
    for (int d = 0; d < DIM; d += 4) {
        d0 = fmaf(xr[d + 0], wr[d + 0], d0);
        d1 = fmaf(xr[d + 1], wr[d + 1], d1);
        d2 = fmaf(xr[d + 2], wr[d + 2], d2);
        d3 = fmaf(xr[d + 3], wr[d + 3], d3);
    }
    return wsqc - 2.f * ((d0 + d1) + (d2 + d3));
}

// ---------------- wsq: |w_k|^2 (exact r3 order) + zero hist/mse ----------------
__global__ __launch_bounds__(256) void som_wsq(const float* __restrict__ w,
                                               float* __restrict__ wsq,
                                               int* __restrict__ hist,
                                               double* __restrict__ mse_acc)
{
    int k = blockIdx.x * 256 + threadIdx.x;   // grid = 2
    const float4* r = reinterpret_cast<const float4*>(w + (size_t)k * DIM);
    float s0 = 0.f, s1 = 0.f, s2 = 0.f, s3 = 0.f;
    #pragma unroll 8
    for (int q = 0; q < DIM / 4; ++q) {
        float4 v = r[q];
        s0 = fmaf(v.x, v.x, s0);
        s1 = fmaf(v.y, v.y, s1);
        s2 = fmaf(v.z, v.z, s2);
        s3 = fmaf(v.w, v.w, s3);
    }
    wsq[k] = (s0 + s1) + (s2 + s3);
    hist[k] = 0;
    if (k == 0) *mse_acc = 0.0;
}

// ---------------- conv: split-f16 conversion of w into fragment order ----------------
// 64 blocks x 256 threads; each thread converts one h8 unit (8 k's of one code row).
__global__ __launch_bounds__(256) void som_conv(const float* __restrict__ w,
                                                _Float16* __restrict__ wfh,
                                                _Float16* __restrict__ wfl)
{
    const int tid = threadIdx.x;
    const int row = blockIdx.x * 8 + (tid >> 5);   // code row
    const int g   = tid & 31;                      // h8 unit within row
    const float4* r = reinterpret_cast<const float4*>(w + (size_t)row * DIM);
    float4 a = r[g * 2], b = r[g * 2 + 1];
    h8 hv, lv; cvt_split8(a, b, hv, lv);
    int dsl = g >> 2, kg = g & 3;
    int ctg = row >> 4, l15 = row & 15;
    size_t off = (((size_t)(ctg * 8 + dsl)) * 4 + kg) * 128 + l15 * 8;
    *reinterpret_cast<h8*>(wfh + off) = hv;
    *reinterpret_cast<h8*>(wfl + off) = lv;
}

// ---------------- main: swapped-operand split-fp16 MFMA argmin ----------------
// 512 threads = 8 waves; wave wid owns codes [wid*64, wid*64+64) = 4 tiles of 16.
// C[code][pt] = mfma(w_frag, x_frag): lane (kg,l15) holds codes kg*4+reg of each
// tile for point col l15 -> top-2 is in-lane; cross-lane only masks 16/32.
__global__ __launch_bounds__(512) void som_main(const float* __restrict__ x,
                                                const float* __restrict__ w,
                                                const _Float16* __restrict__ wfh,
                                                const _Float16* __restrict__ wfl,
                                                float* __restrict__ out,
                                                const float* __restrict__ wsq,
                                                int* __restrict__ hist,
                                                double* __restrict__ mse_acc)
{
    alignas(16) __shared__ _Float16 xh[BM * XSTR];   // 33,792 B
    alignas(16) __shared__ _Float16 xl[BM * XSTR];   // 33,792 B
    __shared__ float wsq_s[KC];                      // 2 KB
    __shared__ float red_b[8][BM], red_s[8][BM];     // 4 KB
    __shared__ int   red_ib[8][BM], red_is[8][BM];   // 4 KB
    __shared__ int   bidx_s[BM];
    __shared__ float wsum[8];

    const int tid  = threadIdx.x;
    const int lane = tid & 63;
    const int wid  = tid >> 6;        // wave 0..7: code group of 64
    const int l15  = lane & 15;       // point col / frag row
    const int kg   = lane >> 4;       // k-group 0..3 (and C row group)
    const int ptBlock = blockIdx.x * BM;

    // ---- stage x tile once: split to f16 hi/lo in LDS ----
    const float4* xg4 = reinterpret_cast<const float4*>(x);
    #pragma unroll
    for (int it = 0; it < 4; ++it) {
        int u = it * 512 + tid;       // h8 unit: 64 rows x 32 groups
        int row = u >> 5, c8 = u & 31;
        float4 a = xg4[(size_t)(ptBlock + row) * 64 + c8 * 2];
        float4 b = xg4[(size_t)(ptBlock + row) * 64 + c8 * 2 + 1];
        h8 hv, lv; cvt_split8(a, b, hv, lv);
        *reinterpret_cast<h8*>(&xh[row * XSTR + c8 * 8]) = hv;
        *reinterpret_cast<h8*>(&xl[row * XSTR + c8 * 8]) = lv;
    }
    wsq_s[tid] = wsq[tid];            // 512 threads cover K=512
    __syncthreads();                  // the only barrier before epilogue

    // per-lane top-2 state for point col = ct*16 + l15
    float sb[4], ss[4];
    int   ib[4], is2[4];
    #pragma unroll
    for (int ct = 0; ct < 4; ++ct) { sb[ct] = INFINITY; ss[ct] = INFINITY; ib[ct] = 0; is2[ct] = 0; }

    const int codeBase = wid * 64;

    f32x4 acc[4][4];                  // [rt (code tile)][ct (point tile)]
    #pragma unroll
    for (int rt = 0; rt < 4; ++rt)
        #pragma unroll
        for (int ct = 0; ct < 4; ++ct)
            acc[rt][ct] = (f32x4){0.f, 0.f, 0.f, 0.f};

    #pragma unroll 1
    for (int dsl = 0; dsl < 8; ++dsl) {
        // x fragments (B operand) from LDS: row = ct*16+l15, k = dsl*32+kg*8
        h8 Bh[4], Bl[4];
        #pragma unroll
        for (int ct = 0; ct < 4; ++ct) {
            int off = (ct * 16 + l15) * XSTR + dsl * 32 + kg * 8;
            Bh[ct] = *reinterpret_cast<const h8*>(&xh[off]);
            Bl[ct] = *reinterpret_cast<const h8*>(&xl[off]);
        }
        // w fragments (A operand) straight from global (L2-resident)
        #pragma unroll
        for (int rt = 0; rt < 4; ++rt) {
            int ctg = (codeBase >> 4) + rt;
            size_t off = (((size_t)ctg * 8 + dsl) * 4 + kg) * 128 + l15 * 8;
            h8 Ah = *reinterpret_cast<const h8*>(wfh + off);
            h8 Al = *reinterpret_cast<const h8*>(wfl + off);
            // variant-major: 4 independent chains between dependent MFMAs
            #pragma unroll
            for (int ct = 0; ct < 4; ++ct)
                acc[rt][ct] = __builtin_amdgcn_mfma_f32_16x16x32_f16(Ah, Bh[ct], acc[rt][ct], 0, 0, 0);
            #pragma unroll
            for (int ct = 0; ct < 4; ++ct)
                acc[rt][ct] = __builtin_amdgcn_mfma_f32_16x16x32_f16(Al, Bh[ct], acc[rt][ct], 0, 0, 0);
            #pragma unroll
            for (int ct = 0; ct < 4; ++ct)
                acc[rt][ct] = __builtin_amdgcn_mfma_f32_16x16x32_f16(Ah, Bl[ct], acc[rt][ct], 0, 0, 0);
        }
    }

    // in-lane top-2 scan, codes ascending in (rt, r)
    #pragma unroll
    for (int rt = 0; rt < 4; ++rt) {
        int cbase = codeBase + rt * 16 + kg * 4;
        #pragma unroll
        for (int ct = 0; ct < 4; ++ct) {
            #pragma unroll
            for (int r = 0; r < 4; ++r) {
                int c = cbase + r;
                float d = wsq_s[c] - 2.f * acc[rt][ct][r];
                if (d < sb[ct] || (d == sb[ct] && c < ib[ct])) {
                    ss[ct] = sb[ct]; is2[ct] = ib[ct]; sb[ct] = d; ib[ct] = c;
                } else if (d < ss[ct] || (d == ss[ct] && c < is2[ct])) {
                    ss[ct] = d; is2[ct] = c;
                }
            }
        }
    }

    // cross-lane merge over kg groups only: masks 16, 32
    #pragma unroll
    for (int ct = 0; ct < 4; ++ct) {
        #pragma unroll
        for (int m = 16; m <= 32; m <<= 1) {
            float ob1 = __shfl_xor(sb[ct], m, 64), ob2 = __shfl_xor(ss[ct], m, 64);
            int   oi1 = __shfl_xor(ib[ct], m, 64), oi2 = __shfl_xor(is2[ct], m, 64);
            merge_top2(sb[ct], ib[ct], ss[ct], is2[ct], ob1, oi1, ob2, oi2);
        }
    }
    if (kg == 0) {
        #pragma unroll
        for (int ct = 0; ct < 4; ++ct) {
            int p = ct * 16 + l15;
            red_b[wid][p] = sb[ct];  red_s[wid][p] = ss[ct];
            red_ib[wid][p] = ib[ct]; red_is[wid][p] = is2[ct];
        }
    }
    __syncthreads();

    // cross-wave merge + exact recheck + enc_idx + hist
    if (tid < BM) {
        float b = red_b[0][tid], s = red_s[0][tid];
        int  bi = red_ib[0][tid], si = red_is[0][tid];
        #pragma unroll
        for (int g = 1; g < 8; ++g)
            merge_top2(b, bi, s, si, red_b[g][tid], red_ib[g][tid], red_s[g][tid], red_is[g][tid]);

        if (s - b < EPS) {            // near-tie: resolve in exact fp32 (rare)
            const float* xr = x + (size_t)(ptBlock + tid) * DIM;
            float d1 = exact_dist(xr, w, bi, wsq_s[bi]);
            float d2 = exact_dist(xr, w, si, wsq_s[si]);
            if (d2 < d1 || (d2 == d1 && si < bi)) bi = si;
        }
        bidx_s[tid] = bi;
        out[EOFF + ptBlock + tid] = (float)bi;
        atomicAdd(&hist[bi], 1);
    }
    __syncthreads();

    // quantized write + exact fp32 mse (x re-read L2-hot); 2 points per iter
    {
        int d = tid & 255;
        int ph = tid >> 8;            // 0..1
        float lsum = 0.f;
        for (int pp = 0; pp < BM / 2; ++pp) {
            int p = pp * 2 + ph;
            int c = bidx_s[p];
            float qv = w[(size_t)c * DIM + d];
            float xv = x[(size_t)(ptBlock + p) * DIM + d];
            out[QOFF + (size_t)(ptBlock + p) * DIM + d] = qv;
            float dd = qv - xv;
            lsum = fmaf(dd, dd, lsum);
        }
        #pragma unroll
        for (int m = 32; m; m >>= 1) lsum += __shfl_xor(lsum, m, 64);
        if (lane == 0) wsum[wid] = lsum;
    }
    __syncthreads();
    if (tid == 0) {
        float t = 0.f;
        #pragma unroll
        for (int i = 0; i < 8; ++i) t += wsum[i];
        atomicAdd(mse_acc, (double)t);
    }
}

// ---------------- g[j] = sum_k bmat[j,k] * (wsq[k] + wsq[j] - 2 w_j.w_k) ----------------
__global__ __launch_bounds__(256) void som_g(const float* __restrict__ w,
                                             const float* __restrict__ bmat,
                                             const float* __restrict__ wsq,
                                             float* __restrict__ g)
{
    __shared__ float wj[DIM];
    __shared__ float psum[4];
    const int j = blockIdx.x;
    const int tid = threadIdx.x;
    wj[tid] = w[(size_t)j * DIM + tid];
    __syncthreads();
    const float wsqj = wsq[j];
    float sum = 0.f;
    for (int k = tid; k < KC; k += 256) {
        const float* wk = &w[(size_t)k * DIM];
        float d0 = 0.f, d1 = 0.f, d2 = 0.f, d3 = 0.f;
        #pragma unroll 4
        for (int d = 0; d < DIM; d += 4) {
            d0 = fmaf(wj[d + 0], wk[d + 0], d0);
            d1 = fmaf(wj[d + 1], wk[d + 1], d1);
            d2 = fmaf(wj[d + 2], wk[d + 2], d2);
            d3 = fmaf(wj[d + 3], wk[d + 3], d3);
        }
        float dot = (d0 + d1) + (d2 + d3);
        float t = wsq[k] + wsqj - 2.f * dot;
        sum = fmaf(bmat[(size_t)j * KC + k], t, sum);
    }
    #pragma unroll
    for (int m = 32; m; m >>= 1) sum += __shfl_xor(sum, m, 64);
    int lane = tid & 63, wid = tid >> 6;
    if (lane == 0) psum[wid] = sum;
    __syncthreads();
    if (tid == 0) g[j] = (psum[0] + psum[1]) + (psum[2] + psum[3]);
}

// ---------------- final: perplexity + loss ----------------
__global__ __launch_bounds__(512) void som_final(const int* __restrict__ hist,
                                                 const float* __restrict__ g,
                                                 const double* __restrict__ mse_acc,
                                                 float* __restrict__ out)
{
    __shared__ float e_part[8], k_part[8];
    const int tid = threadIdx.x;
    int cnt = hist[tid];
    float p = (float)cnt / (float)NPTS;
    float ent = -p * logf(p + 1e-10f);
    float koh = (float)cnt * g[tid];
    #pragma unroll
    for (int m = 32; m; m >>= 1) {
        ent += __shfl_xor(ent, m, 64);
        koh += __shfl_xor(koh, m, 64);
    }
    int lane = tid & 63, wid = tid >> 6;
    if (lane == 0) { e_part[wid] = ent; k_part[wid] = koh; }
    __syncthreads();
    if (tid == 0) {
        float es = 0.f, ks = 0.f;
        #pragma unroll
        for (int i = 0; i < 8; ++i) { es += e_part[i]; ks += k_part[i]; }
        float mse = (float)(*mse_acc / (double)(NPTS * (size_t)DIM));
        out[0] = fmaf(1.25f, mse, ks / (float)NPTS);
        out[PIDX] = expf(es);
    }
}

extern "C" void kernel_launch(void* const* d_in, const int* in_sizes, int n_in,
                              void* d_out, int out_size, void* d_ws, size_t ws_size,
                              hipStream_t stream) {
    const float* x    = (const float*)d_in[0];
    const float* w    = (const float*)d_in[1];
    const float* bmat = (const float*)d_in[2];
    float* out = (float*)d_out;

    _Float16* wfh = (_Float16*)d_ws;                         // 256 KB
    _Float16* wfl = wfh + 131072;                            // 256 KB
    float*  wsq  = (float*)((char*)d_ws + 524288);
    float*  g    = (float*)((char*)d_ws + 526336);
    int*    hist = (int*)((char*)d_ws + 528384);
    double* mse  = (double*)((char*)d_ws + 530432);

    som_wsq  <<<2, 256, 0, stream>>>(w, wsq, hist, mse);
    som_conv <<<64, 256, 0, stream>>>(w, wfh, wfl);
    som_main <<<NBLK, 512, 0, stream>>>(x, w, wfh, wfl, out, wsq, hist, mse);
    som_g    <<<KC, 256, 0, stream>>>(w, bmat, wsq, g);
    som_final<<<1, KC, 0, stream>>>(hist, g, mse, out);
}